// Round 10
// baseline (2752.067 us; speedup 1.0000x reference)
//
#include <hip/hip_runtime.h>
#include <hip/hip_bf16.h>

#define N_NODES 50000
#define N_EDGES 640000
#define C_DIM 128
#define B_DIM 64
#define L_DIM 32
#define D_DIM 256
#define S_DIM 128
#define R_DIM 8
#define K_CONV 4
#define GROUP 8
#define SCAN_BLK 49   // ceil(50000/1024)

typedef unsigned short u16;

__device__ __forceinline__ float bu2f(u16 u){ return __uint_as_float(((unsigned)u) << 16); }
__device__ __forceinline__ u16 f2bu(float f){
  __hip_bfloat16 h = __float2bfloat16(f);
  return *reinterpret_cast<u16*>(&h);
}
__device__ __forceinline__ float sigmoidf_(float x){ return 1.f/(1.f + expf(-x)); }
__device__ __forceinline__ int clampi(int v, int lo, int hi){ return max(lo, min(v, hi)); }
__device__ __forceinline__ float ldf(const void* p, size_t i, int f){
  return f ? bu2f(((const u16*)p)[i]) : ((const float*)p)[i];
}
__device__ __forceinline__ void stf(void* p, size_t i, int f, float v){
  if (f) ((u16*)p)[i] = f2bu(v); else ((float*)p)[i] = v;
}

// weight arena layout (element offsets); 27 segments in d_in[4..30] order
constexpr int K_SEG = 27;
constexpr int kCum[K_SEG+1] = {
  0, 2048, 3072, 134144, 135168, 184320, 233472, 233856, 234240, 299776,
  300800, 301056, 368640, 370688, 370944, 403712, 403968, 436736, 436864,
  436992, 584448, 584576, 584704, 584832, 601216, 601344, 601472, 601600 };
#define ARENA_TOTAL 601600

struct Ptrs { const void* p[K_SEG]; };

// ---------------- detection (64-lane parallel) ----------------

__global__ void detect_kernel(const unsigned* dp_bits, const unsigned* cand1,
                              const unsigned* cand2, int* flags){
  int lane = threadIdx.x & 63;
  unsigned idx = (unsigned)((lane * 9973u) % (unsigned)N_EDGES);
  int v1 = (cand1[idx] < (unsigned)N_NODES) ? 1 : 0;
  int v2 = (cand2[idx] < (unsigned)N_NODES) ? 1 : 0;
  unsigned long long m1 = __ballot(v1);
  unsigned long long m2 = __ballot(v2);
  if (lane == 0){
    flags[0] = (dp_bits[0] == 0x3F803F80u) ? 1 : 0;
    flags[1] = (__popcll(m1) > __popcll(m2)) ? 1 : 0;   // 1 => d_in[1] is edge_index
  }
}

// ---------------- fused weight-convert ----------------

__global__ __launch_bounds__(256) void cvt_all_kernel(Ptrs ptrs, float* arena,
                                                      const int* flags){
  int i = blockIdx.x*256 + threadIdx.x;
  if (i >= ARENA_TOTAL) return;
  int lo = 0, hi = K_SEG;
  #pragma unroll
  for (int it = 0; it < 5; it++){
    int mid = (lo + hi) >> 1;
    if (i >= kCum[mid]) lo = mid; else hi = mid;
  }
  int elem = i - kCum[lo];
  const void* sp = ptrs.p[lo];
  arena[i] = flags[0] ? bu2f(((const u16*)sp)[elem]) : ((const float*)sp)[elem];
}

// ---------------- counting sort of edges by dst ----------------

__global__ void hist_kernel(const int* __restrict__ eiA, const int* __restrict__ eiB,
                            const int* __restrict__ flags, int* __restrict__ hist){
  const int* dst = (flags[1] ? eiA : eiB) + N_EDGES;
  int e = blockIdx.x*256 + threadIdx.x;
  if (e >= N_EDGES) return;
  int d = clampi(dst[e], 0, N_NODES-1);
  atomicAdd(&hist[d], 1);
}

// 3-phase parallel scan: local inclusive -> block sums -> add back (exclusive)
__global__ __launch_bounds__(1024) void scan1_kernel(const int* __restrict__ hist,
                                                     int* __restrict__ tmp,
                                                     int* __restrict__ bsums){
  __shared__ int buf[1024];
  int b = blockIdx.x, tid = threadIdx.x;
  int i = b*1024 + tid;
  int v = (i < N_NODES) ? hist[i] : 0;
  buf[tid] = v;
  __syncthreads();
  for (int off = 1; off < 1024; off <<= 1){
    int t = (tid >= off) ? buf[tid-off] : 0;
    __syncthreads();
    buf[tid] += t;
    __syncthreads();
  }
  if (i < N_NODES) tmp[i] = buf[tid];       // inclusive
  if (tid == 1023) bsums[b] = buf[1023];
}

__global__ void scan2_kernel(int* __restrict__ bsums, int* __restrict__ offsets){
  if (threadIdx.x == 0){
    int run = 0;
    for (int b = 0; b < SCAN_BLK; b++){ int v = bsums[b]; bsums[b] = run; run += v; }
    offsets[N_NODES] = run;
  }
}

__global__ __launch_bounds__(1024) void scan3_kernel(int* __restrict__ offsets,
                                                     int* __restrict__ hist,
                                                     const int* __restrict__ bsums){
  int b = blockIdx.x, tid = threadIdx.x;
  int i = b*1024 + tid;
  if (i >= N_NODES) return;
  int incl = offsets[i];
  int h = hist[i];
  int excl = incl - h + bsums[b];
  offsets[i] = excl;
  hist[i] = excl;       // cursor copy for perm_kernel
}

__global__ void perm_kernel(const int* __restrict__ eiA, const int* __restrict__ eiB,
                            const int* __restrict__ flags, int* __restrict__ cursor,
                            int* __restrict__ perm){
  const int* dst = (flags[1] ? eiA : eiB) + N_EDGES;
  int e = blockIdx.x*256 + threadIdx.x;
  if (e >= N_EDGES) return;
  int d = clampi(dst[e], 0, N_NODES-1);
  int pos = atomicAdd(&cursor[d], 1);
  pos = clampi(pos, 0, N_EDGES-1);
  perm[pos] = e;
}

// ---------------- pooling ----------------

__global__ __launch_bounds__(128) void pool_kernel(
    const void* __restrict__ xv, const int* __restrict__ batch,
    float* __restrict__ xsum, int* __restrict__ counts, const int* __restrict__ flags)
{
  int c = threadIdx.x;
  int f = flags[0];
  int n0 = blockIdx.x * 32;
  int nend = min(n0 + 32, N_NODES);
  float acc = 0.f; int cnt = 0;
  int curb = clampi(batch[n0], 0, B_DIM-1);
  for (int n = n0; n < nend; n++){
    int b = clampi(batch[n], 0, B_DIM-1);
    if (b != curb){
      atomicAdd(&xsum[curb*C_DIM + c], acc);
      if (c == 0) atomicAdd(&counts[curb], cnt);
      acc = 0.f; cnt = 0; curb = b;
    }
    acc += ldf(xv, (size_t)n*C_DIM + c, f);
    cnt++;
  }
  atomicAdd(&xsum[curb*C_DIM + c], acc);
  if (c == 0) atomicAdd(&counts[curb], cnt);
}

// ---------------- GRU (+ mean finalize folded in) ----------------

__global__ __launch_bounds__(384) void gru_kernel(
    const float* __restrict__ xsum, const int* __restrict__ counts,
    const float* __restrict__ Wih, const float* __restrict__ bih,
    const float* __restrict__ Whh, const float* __restrict__ bhh,
    float* __restrict__ tokens)
{
  int b = blockIdx.x, j = threadIdx.x;  // j in [0,384)
  __shared__ float xm[C_DIM], h[C_DIM], gh[3*C_DIM], sgi[3*C_DIM];
  __shared__ float mxS;
  if (j == 0){
    int m = 1;
    for (int bb = 0; bb < B_DIM; bb++) m = max(m, counts[bb]);
    mxS = (float)m;
  }
  __syncthreads();
  if (j < C_DIM){ xm[j] = xsum[b*C_DIM + j] / mxS; h[j] = 0.f; }
  __syncthreads();
  float gi = bih[j];
  for (int k = 0; k < C_DIM; k++) gi = fmaf(xm[k], Wih[k*384 + j], gi);
  sgi[j] = gi;
  __syncthreads();
  for (int t = 0; t < L_DIM; t++){
    float acc = bhh[j];
    #pragma unroll 4
    for (int k = 0; k < C_DIM; k++) acc = fmaf(h[k], Whh[k*384 + j], acc);
    gh[j] = acc;
    __syncthreads();
    if (j < C_DIM){
      float r  = sigmoidf_(sgi[j] + gh[j]);
      float z  = sigmoidf_(sgi[C_DIM + j] + gh[C_DIM + j]);
      float nn = tanhf(sgi[2*C_DIM + j] + r*gh[2*C_DIM + j]);
      float hn = (1.f - z)*nn + z*h[j];
      h[j] = hn;
      tokens[((size_t)b*L_DIM + t)*C_DIM + j] = hn;
    }
    __syncthreads();
  }
}

// ---------------- token projection (Win) ----------------

__global__ __launch_bounds__(256) void token_proj_kernel(
    const float* __restrict__ tokens, const float* __restrict__ Win,
    float* __restrict__ x_in, float* __restrict__ z_last)
{
  int row = blockIdx.x;   // b*L + t
  int d = threadIdx.x;    // [0,256)
  __shared__ float tok[C_DIM];
  if (d < C_DIM) tok[d] = tokens[(size_t)row*C_DIM + d];
  __syncthreads();
  float acc = 0.f;
  for (int k = 0; k < C_DIM; k++) acc = fmaf(tok[k], Win[k*512 + d], acc);
  x_in[(size_t)row*D_DIM + d] = acc;
  if ((row & (L_DIM-1)) == L_DIM-1){
    float acc2 = 0.f;
    for (int k = 0; k < C_DIM; k++) acc2 = fmaf(tok[k], Win[k*512 + D_DIM + d], acc2);
    z_last[(row >> 5)*D_DIM + d] = acc2;
  }
}

// ---------------- xproj (conv+silu folded in) ----------------

__global__ __launch_bounds__(256) void xproj_kernel(
    const float* __restrict__ x_in, const float* __restrict__ cw,
    const float* __restrict__ cb, const float* __restrict__ Wx,
    const float* __restrict__ Wdt, const float* __restrict__ bdt,
    float* __restrict__ dt, float* __restrict__ Bp, float* __restrict__ Cp,
    float* __restrict__ x_c)
{
  int row = blockIdx.x; int tid = threadIdx.x;  // tid = d in [0,256)
  int t = row & (L_DIM-1);
  __shared__ float xr[D_DIM];
  __shared__ float dtr[R_DIM];
  float acc0 = cb[tid];
  #pragma unroll
  for (int k = 0; k < K_CONV; k++){
    int tt = t + k - (K_CONV-1);
    if (tt >= 0) acc0 = fmaf(cw[tid*K_CONV + k], x_in[(size_t)(row + tt - t)*D_DIM + tid], acc0);
  }
  float xcv = acc0 * sigmoidf_(acc0);
  x_c[(size_t)row*D_DIM + tid] = xcv;
  xr[tid] = xcv;
  __syncthreads();
  float acc = 0.f;
  #pragma unroll 4
  for (int k = 0; k < D_DIM; k++) acc = fmaf(xr[k], Wx[k*264 + tid], acc);
  if (tid < R_DIM)              dtr[tid] = acc;
  else if (tid < R_DIM+S_DIM)   Bp[(size_t)row*S_DIM + tid - R_DIM] = acc;
  else                          Cp[(size_t)row*S_DIM + tid - (R_DIM+S_DIM)] = acc;
  if (tid < 264 - D_DIM){
    float acc2 = 0.f;
    #pragma unroll 4
    for (int k = 0; k < D_DIM; k++) acc2 = fmaf(xr[k], Wx[k*264 + D_DIM + tid], acc2);
    Cp[(size_t)row*S_DIM + (D_DIM - (R_DIM+S_DIM)) + tid] = acc2;
  }
  __syncthreads();
  float a = bdt[tid];
  #pragma unroll
  for (int r = 0; r < R_DIM; r++) a = fmaf(dtr[r], Wdt[r*D_DIM + tid], a);
  dt[(size_t)row*D_DIM + tid] = (a > 20.f) ? a : log1pf(expf(a));
}

// ---------------- SSM scan ----------------

__global__ __launch_bounds__(256) void ssm_kernel(
    const float* __restrict__ dt, const float* __restrict__ Bp,
    const float* __restrict__ Cp, const float* __restrict__ x_c,
    const float* __restrict__ A_log, const float* __restrict__ Dp_,
    const float* __restrict__ z_last, float* __restrict__ y_last)
{
  int wid = (blockIdx.x*256 + threadIdx.x) >> 6;
  int lane = threadIdx.x & 63;
  int b = wid >> 8, d = wid & (D_DIM-1);
  int s0 = lane*2;
  float A0 = -expf(A_log[d*S_DIM + s0]);
  float A1 = -expf(A_log[d*S_DIM + s0 + 1]);
  float h0 = 0.f, h1 = 0.f;
  for (int t = 0; t < L_DIM; t++){
    int row = b*L_DIM + t;
    float dtv = dt[(size_t)row*D_DIM + d];
    float xv  = x_c[(size_t)row*D_DIM + d];
    float bx = dtv * xv;
    float2 Bv = ((const float2*)(Bp + (size_t)row*S_DIM))[lane];
    h0 = fmaf(expf(dtv*A0), h0, bx*Bv.x);
    h1 = fmaf(expf(dtv*A1), h1, bx*Bv.y);
  }
  int row = b*L_DIM + (L_DIM-1);
  float2 Cv = ((const float2*)(Cp + (size_t)row*S_DIM))[lane];
  float y = h0*Cv.x + h1*Cv.y;
  #pragma unroll
  for (int off = 32; off; off >>= 1) y += __shfl_down(y, off);
  if (lane == 0){
    float xc = x_c[(size_t)row*D_DIM + d];
    float yv = y + Dp_[d]*xc;
    float z  = z_last[b*D_DIM + d];
    yv *= z * sigmoidf_(z);
    y_last[b*D_DIM + d] = yv;
  }
}

// ---------------- proj = ln(y_last @ Wout) @ Wm1[8C:] ----------------

__device__ __forceinline__ float block_sum_128(float v, float* red){
  int c = threadIdx.x;
  red[c] = v; __syncthreads();
  if (c < 64) red[c] += red[c+64];
  __syncthreads();
  if (c < 64){
    float r = red[c];
    #pragma unroll
    for (int off = 32; off; off >>= 1) r += __shfl_down(r, off);
    if (c == 0) red[0] = r;
  }
  __syncthreads();
  float out = red[0];
  __syncthreads();
  return out;
}

__global__ __launch_bounds__(128) void xm_kernel(
    const float* __restrict__ y_last, const float* __restrict__ Wout,
    const float* __restrict__ g_m, const float* __restrict__ b_m,
    const float* __restrict__ Wm1x, float* __restrict__ proj)
{
  int b = blockIdx.x, c = threadIdx.x;
  __shared__ float yr[D_DIM];
  __shared__ float red[C_DIM];
  __shared__ float xmr[C_DIM];
  yr[c]        = y_last[b*D_DIM + c];
  yr[C_DIM+c]  = y_last[b*D_DIM + C_DIM + c];
  __syncthreads();
  float acc = 0.f;
  for (int k = 0; k < D_DIM; k++) acc = fmaf(yr[k], Wout[k*C_DIM + c], acc);
  float mean = block_sum_128(acc, red) * (1.f/C_DIM);
  float dv = acc - mean;
  float var = block_sum_128(dv*dv, red) * (1.f/C_DIM);
  float mo = dv*rsqrtf(var + 1e-5f)*g_m[c] + b_m[c];
  xmr[c] = mo;
  __syncthreads();
  float p = 0.f;
  for (int k = 0; k < C_DIM; k++) p = fmaf(xmr[k], Wm1x[k*C_DIM + c], p);
  proj[b*C_DIM + c] = p;
}

// ---------------- fused graph path + mlp1 + mlp2 + final LN -> d_out ----------------
// 256 threads: c = tid&127, half = tid>>7; half owns nodes half*4..half*4+3 in ALL phases.
// Gather: r9's per-thread loop with 4-deep prefetch. Matmuls: scalar coalesced W + b128 LDS.

__device__ __forceinline__ float half_sum_128(float v, float (*red)[C_DIM], int half, int c){
  red[half][c] = v; __syncthreads();
  if (c < 64) red[half][c] += red[half][c+64];
  __syncthreads();
  if (c < 64){
    float r = red[half][c];
    #pragma unroll
    for (int off = 32; off; off >>= 1) r += __shfl_down(r, off);
    if (c == 0) red[half][0] = r;
  }
  __syncthreads();
  float out = red[half][0];
  __syncthreads();
  return out;
}

__global__ __launch_bounds__(256) void graph_kernel(
    const void* __restrict__ xv,
    const void* __restrict__ in1, const void* __restrict__ in2,
    const int* __restrict__ perm, const int* __restrict__ offsets,
    const float* __restrict__ WeF, const float* __restrict__ beF,
    const float* __restrict__ WcF, const float* __restrict__ bcF,
    const float* __restrict__ Wm1F, const float* __restrict__ bm1F,
    const float* __restrict__ proj, const int* __restrict__ batch,
    const float* __restrict__ ghF, const float* __restrict__ bhF,
    const float* __restrict__ Wm2F, const float* __restrict__ bm2F,
    const float* __restrict__ goF, const float* __restrict__ boF,
    const int* __restrict__ flags, void* __restrict__ out)
{
  const int tid  = threadIdx.x;
  const int c    = tid & (C_DIM-1);
  const int half = tid >> 7;
  const int gb   = half*4;
  const int f = flags[0];
  const int* src = (const int*)(flags[1] ? in1 : in2);
  const void* eav = flags[1] ? in2 : in1;
  const u16*  x16 = (const u16*)xv;  const float* x32 = (const float*)xv;
  const u16*  e16 = (const u16*)eav; const float* e32 = (const float*)eav;

  __shared__ __align__(16) float aggS[GROUP][8][C_DIM];  // 32 KB
  __shared__ __align__(16) float xsS[GROUP][C_DIM];      // 4 KB
  __shared__ __align__(16) float h1S[GROUP][C_DIM];      // 4 KB
  __shared__ float red[2][C_DIM];                        // 1 KB

  float we0[8], we1[8], beh[8];
  #pragma unroll
  for (int h = 0; h < 8; h++){
    we0[h] = WeF[h*2*C_DIM + c];
    we1[h] = WeF[h*2*C_DIM + C_DIM + c];
    beh[h] = beF[h*C_DIM + c];
  }
  const int nbase = blockIdx.x * GROUP;

  // ---- phase 1: edge gather, 4-deep register prefetch pipeline ----
  for (int g = gb; g < gb + 4; g++){
    int n = nbase + g;
    int q0 = clampi(offsets[n],   0, N_EDGES);
    int q1 = clampi(offsets[n+1], q0, N_EDGES);
    int cnt = q1 - q0;                    // wave-uniform (same node for all lanes)
    float a[8] = {0,0,0,0,0,0,0,0};
    float xP[4], a0P[4], a1P[4];
    #pragma unroll
    for (int d = 0; d < 4; d++){
      xP[d] = 0.f; a0P[d] = 0.f; a1P[d] = 0.f;
      if (d < cnt){
        int e = clampi(perm[q0 + d], 0, N_EDGES-1);
        int s = clampi(src[e], 0, N_NODES-1);
        if (f){ a0P[d] = bu2f(e16[2*e]); a1P[d] = bu2f(e16[2*e+1]); }
        else  { a0P[d] = e32[2*e];       a1P[d] = e32[2*e+1]; }
        xP[d] = f ? bu2f(x16[(size_t)s*C_DIM + c]) : x32[(size_t)s*C_DIM + c];
      }
    }
    for (int j = 0; j < cnt; j += 4){
      float xC[4], a0C[4], a1C[4];
      #pragma unroll
      for (int d = 0; d < 4; d++){ xC[d] = xP[d]; a0C[d] = a0P[d]; a1C[d] = a1P[d]; }
      #pragma unroll
      for (int d = 0; d < 4; d++){
        int jn = j + 4 + d;
        if (jn < cnt){
          int e = clampi(perm[q0 + jn], 0, N_EDGES-1);
          int s = clampi(src[e], 0, N_NODES-1);
          if (f){ a0P[d] = bu2f(e16[2*e]); a1P[d] = bu2f(e16[2*e+1]); }
          else  { a0P[d] = e32[2*e];       a1P[d] = e32[2*e+1]; }
          xP[d] = f ? bu2f(x16[(size_t)s*C_DIM + c]) : x32[(size_t)s*C_DIM + c];
        }
      }
      #pragma unroll
      for (int d = 0; d < 4; d++){
        if (j + d < cnt){
          #pragma unroll
          for (int h = 0; h < 8; h++)
            a[h] += fmaxf(fmaf(a0C[d], we0[h], fmaf(a1C[d], we1[h], xC[d] + beh[h])), 0.f);
        }
      }
    }
    #pragma unroll
    for (int h = 0; h < 8; h++) aggS[g][h][c] = a[h];
  }
  __syncthreads();

  // ---- phase 2: per-head matmuls (scalar coalesced W, b128 LDS broadcasts) ----
  float p[4] = {0,0,0,0};
  for (int h = 0; h < 8; h++){
    float accg[4];
    #pragma unroll
    for (int i = 0; i < 4; i++) accg[i] = bcF[h*C_DIM + c];
    const float* wc = WcF + (size_t)h*C_DIM*C_DIM;
    for (int k4 = 0; k4 < C_DIM/4; k4++){
      float w0 = wc[(k4*4+0)*C_DIM + c];
      float w1 = wc[(k4*4+1)*C_DIM + c];
      float w2 = wc[(k4*4+2)*C_DIM + c];
      float w3 = wc[(k4*4+3)*C_DIM + c];
      #pragma unroll
      for (int i = 0; i < 4; i++){
        float4 av = *(const float4*)&aggS[gb+i][h][k4*4];
        accg[i] = fmaf(av.x, w0, fmaf(av.y, w1, fmaf(av.z, w2, fmaf(av.w, w3, accg[i]))));
      }
    }
    __syncthreads();   // prior h's xsS readers done
    #pragma unroll
    for (int i = 0; i < 4; i++) xsS[gb+i][c] = fmaxf(accg[i], 0.f);
    __syncthreads();
    const float* wm = Wm1F + (size_t)h*C_DIM*C_DIM;
    for (int k4 = 0; k4 < C_DIM/4; k4++){
      float w0 = wm[(k4*4+0)*C_DIM + c];
      float w1 = wm[(k4*4+1)*C_DIM + c];
      float w2 = wm[(k4*4+2)*C_DIM + c];
      float w3 = wm[(k4*4+3)*C_DIM + c];
      #pragma unroll
      for (int i = 0; i < 4; i++){
        float4 xi = *(const float4*)&xsS[gb+i][k4*4];
        p[i] = fmaf(xi.x, w0, fmaf(xi.y, w1, fmaf(xi.z, w2, fmaf(xi.w, w3, p[i]))));
      }
    }
  }

  // ---- phase 3: mlp1 LN + relu -> h1S ----
  for (int i = 0; i < 4; i++){
    int g = gb + i;
    int n = nbase + g;
    int bi = clampi(batch[n], 0, B_DIM-1);
    float val = p[i] + bm1F[c] + proj[bi*C_DIM + c];
    float mean = half_sum_128(val, red, half, c) * (1.f/C_DIM);
    float dv = val - mean;
    float var = half_sum_128(dv*dv, red, half, c) * (1.f/C_DIM);
    float v = dv*rsqrtf(var + 1e-5f)*ghF[c] + bhF[c];
    h1S[g][c] = fmaxf(v, 0.f);
  }
  __syncthreads();

  // ---- phase 4: mlp2 (b128 LDS) + residual + final LN -> out ----
  float acc2[4];
  #pragma unroll
  for (int i = 0; i < 4; i++) acc2[i] = bm2F[c];
  for (int k4 = 0; k4 < C_DIM/4; k4++){
    float w0 = Wm2F[(k4*4+0)*C_DIM + c];
    float w1 = Wm2F[(k4*4+1)*C_DIM + c];
    float w2 = Wm2F[(k4*4+2)*C_DIM + c];
    float w3 = Wm2F[(k4*4+3)*C_DIM + c];
    #pragma unroll
    for (int i = 0; i < 4; i++){
      float4 hv = *(const float4*)&h1S[gb+i][k4*4];
      acc2[i] = fmaf(hv.x, w0, fmaf(hv.y, w1, fmaf(hv.z, w2, fmaf(hv.w, w3, acc2[i]))));
    }
  }
  for (int i = 0; i < 4; i++){
    int n = nbase + gb + i;
    float acc = acc2[i] + ldf(xv, (size_t)n*C_DIM + c, f);
    float mean = half_sum_128(acc, red, half, c) * (1.f/C_DIM);
    float dv = acc - mean;
    float var = half_sum_128(dv*dv, red, half, c) * (1.f/C_DIM);
    float v = dv*rsqrtf(var + 1e-5f)*goF[c] + boF[c];
    stf(out, (size_t)n*C_DIM + c, f, v);
  }
}

// ---------------- launcher ----------------

extern "C" void kernel_launch(void* const* d_in, const int* in_sizes, int n_in,
                              void* d_out, int out_size, void* d_ws, size_t ws_size,
                              hipStream_t stream)
{
  const void* x      = d_in[0];
  const void* in1    = d_in[1];
  const void* in2    = d_in[2];
  const int*  batch  = (const int*)d_in[3];
  (void)in_sizes; (void)n_in; (void)out_size; (void)ws_size;

  char* ws = (char*)d_ws;
  size_t off = 0;
  auto alloc = [&](size_t nbytes)->char*{
    char* p = ws + off;
    off += (nbytes + 255) & ~(size_t)255;
    return p;
  };
  int*   flags = (int*)alloc(8);
  float* arena = (float*)alloc((size_t)ARENA_TOTAL*4);
  int* hist    = (int*)alloc((size_t)N_NODES*4);          // becomes cursor after scan
  int* offsets = (int*)alloc((size_t)(N_NODES+1)*4);
  int* perm    = (int*)alloc((size_t)N_EDGES*4);
  int* bsums   = (int*)alloc((size_t)SCAN_BLK*4);
  float* proj   = (float*)alloc((size_t)B_DIM*C_DIM*4);
  float* xsum   = (float*)alloc((size_t)B_DIM*C_DIM*4);
  int*   counts = (int*)alloc((size_t)B_DIM*4);
  float* tokens = (float*)alloc((size_t)B_DIM*L_DIM*C_DIM*4);  // reused as Bp
  float* x_in   = (float*)alloc((size_t)B_DIM*L_DIM*D_DIM*4);  // reused as dtb
  float* x_c    = (float*)alloc((size_t)B_DIM*L_DIM*D_DIM*4);
  float* Cp     = (float*)alloc((size_t)B_DIM*L_DIM*S_DIM*4);
  float* z_last = (float*)alloc((size_t)B_DIM*D_DIM*4);
  float* y_last = (float*)alloc((size_t)B_DIM*D_DIM*4);
  float* Bp  = tokens;
  float* dtb = x_in;

  // weight arena views (match kCum)
  float* WeF   = arena + 0;      float* beF   = arena + 2048;
  float* WcF   = arena + 3072;   float* bcF   = arena + 134144;
  float* WihF  = arena + 135168; float* WhhF  = arena + 184320;
  float* bihF  = arena + 233472; float* bhhF  = arena + 233856;
  float* WinF  = arena + 234240; float* cwF   = arena + 299776;
  float* cbF   = arena + 300800; float* WxF   = arena + 301056;
  float* WdtF  = arena + 368640; float* bdtF  = arena + 370688;
  float* AlF   = arena + 370944; float* DpF   = arena + 403712;
  float* WoutF = arena + 403968; float* gmF   = arena + 436736;
  float* bmF   = arena + 436864; float* Wm1F  = arena + 436992;
  float* bm1F  = arena + 584448; float* ghF   = arena + 584576;
  float* bhF   = arena + 584704; float* Wm2F  = arena + 584832;
  float* bm2F  = arena + 601216; float* goF   = arena + 601344;
  float* boF   = arena + 601472;

  // 0) detect dtype + edge-input order
  detect_kernel<<<1, 64, 0, stream>>>((const unsigned*)d_in[19],
                                      (const unsigned*)in1, (const unsigned*)in2, flags);

  // 1) all weight converts in one launch
  Ptrs ptrs;
  for (int i = 0; i < K_SEG; i++) ptrs.p[i] = d_in[4 + i];
  cvt_all_kernel<<<(ARENA_TOTAL + 255)/256, 256, 0, stream>>>(ptrs, arena, flags);

  // 2) counting sort of edges by dst (3-phase parallel scan)
  hipMemsetAsync(hist, 0, (size_t)N_NODES*4, stream);
  hist_kernel<<<(N_EDGES + 255)/256, 256, 0, stream>>>((const int*)in1, (const int*)in2, flags, hist);
  scan1_kernel<<<SCAN_BLK, 1024, 0, stream>>>(hist, offsets, bsums);
  scan2_kernel<<<1, 64, 0, stream>>>(bsums, offsets);
  scan3_kernel<<<SCAN_BLK, 1024, 0, stream>>>(offsets, hist, bsums);
  perm_kernel<<<(N_EDGES + 255)/256, 256, 0, stream>>>((const int*)in1, (const int*)in2, flags, hist, perm);

  // 3) sequential path
  hipMemsetAsync(xsum, 0, (size_t)B_DIM*C_DIM*4 + 256, stream);  // xsum + counts
  pool_kernel<<<(N_NODES + 31)/32, 128, 0, stream>>>(x, batch, xsum, counts, flags);
  gru_kernel<<<B_DIM, 384, 0, stream>>>(xsum, counts, WihF, bihF, WhhF, bhhF, tokens);
  token_proj_kernel<<<B_DIM*L_DIM, 256, 0, stream>>>(tokens, WinF, x_in, z_last);
  xproj_kernel<<<B_DIM*L_DIM, 256, 0, stream>>>(x_in, cwF, cbF, WxF, WdtF, bdtF, dtb, Bp, Cp, x_c);
  ssm_kernel<<<(B_DIM*D_DIM)/4, 256, 0, stream>>>(dtb, Bp, Cp, x_c, AlF, DpF, z_last, y_last);
  xm_kernel<<<B_DIM, 128, 0, stream>>>(y_last, WoutF, gmF, bmF, Wm1F + 8*C_DIM*C_DIM, proj);

  // 4) fused graph path + mlp1 + mlp2 + final LN -> d_out
  graph_kernel<<<N_NODES/GROUP, 256, 0, stream>>>(
      x, in1, in2, perm, offsets, WeF, beF, WcF, bcF, Wm1F, bm1F,
      proj, batch, ghF, bhF, Wm2F, bm2F, goF, boF, flags, d_out);
}

// Round 11
// 1250.503 us; speedup vs baseline: 2.2008x; 2.2008x over previous
//
#include <hip/hip_runtime.h>
#include <hip/hip_bf16.h>

#define N_NODES 50000
#define N_EDGES 640000
#define C_DIM 128
#define B_DIM 64
#define L_DIM 32
#define D_DIM 256
#define S_DIM 128
#define R_DIM 8
#define K_CONV 4
#define GROUP 4
#define SCAN_BLK 49   // ceil(50000/1024)

typedef unsigned short u16;

__device__ __forceinline__ float bu2f(u16 u){ return __uint_as_float(((unsigned)u) << 16); }
__device__ __forceinline__ u16 f2bu(float f){
  __hip_bfloat16 h = __float2bfloat16(f);
  return *reinterpret_cast<u16*>(&h);
}
__device__ __forceinline__ float sigmoidf_(float x){ return 1.f/(1.f + expf(-x)); }
__device__ __forceinline__ int clampi(int v, int lo, int hi){ return max(lo, min(v, hi)); }
__device__ __forceinline__ float ldf(const void* p, size_t i, int f){
  return f ? bu2f(((const u16*)p)[i]) : ((const float*)p)[i];
}
__device__ __forceinline__ void stf(void* p, size_t i, int f, float v){
  if (f) ((u16*)p)[i] = f2bu(v); else ((float*)p)[i] = v;
}

// weight arena layout (element offsets); 27 segments in d_in[4..30] order
constexpr int K_SEG = 27;
constexpr int kCum[K_SEG+1] = {
  0, 2048, 3072, 134144, 135168, 184320, 233472, 233856, 234240, 299776,
  300800, 301056, 368640, 370688, 370944, 403712, 403968, 436736, 436864,
  436992, 584448, 584576, 584704, 584832, 601216, 601344, 601472, 601600 };
#define ARENA_TOTAL 601600

struct Ptrs { const void* p[K_SEG]; };

// ---------------- detection (64-lane parallel) ----------------

__global__ void detect_kernel(const unsigned* dp_bits, const unsigned* cand1,
                              const unsigned* cand2, int* flags){
  int lane = threadIdx.x & 63;
  unsigned idx = (unsigned)((lane * 9973u) % (unsigned)N_EDGES);
  int v1 = (cand1[idx] < (unsigned)N_NODES) ? 1 : 0;
  int v2 = (cand2[idx] < (unsigned)N_NODES) ? 1 : 0;
  unsigned long long m1 = __ballot(v1);
  unsigned long long m2 = __ballot(v2);
  if (lane == 0){
    flags[0] = (dp_bits[0] == 0x3F803F80u) ? 1 : 0;
    flags[1] = (__popcll(m1) > __popcll(m2)) ? 1 : 0;   // 1 => d_in[1] is edge_index
  }
}

// ---------------- fused weight-convert ----------------

__global__ __launch_bounds__(256) void cvt_all_kernel(Ptrs ptrs, float* arena,
                                                      const int* flags){
  int i = blockIdx.x*256 + threadIdx.x;
  if (i >= ARENA_TOTAL) return;
  int lo = 0, hi = K_SEG;
  #pragma unroll
  for (int it = 0; it < 5; it++){
    int mid = (lo + hi) >> 1;
    if (i >= kCum[mid]) lo = mid; else hi = mid;
  }
  int elem = i - kCum[lo];
  const void* sp = ptrs.p[lo];
  arena[i] = flags[0] ? bu2f(((const u16*)sp)[elem]) : ((const float*)sp)[elem];
}

// ---------------- counting sort of edges by dst ----------------

__global__ void hist_kernel(const int* __restrict__ eiA, const int* __restrict__ eiB,
                            const int* __restrict__ flags, int* __restrict__ hist){
  const int* dst = (flags[1] ? eiA : eiB) + N_EDGES;
  int e = blockIdx.x*256 + threadIdx.x;
  if (e >= N_EDGES) return;
  int d = clampi(dst[e], 0, N_NODES-1);
  atomicAdd(&hist[d], 1);
}

// 3-phase parallel scan: local inclusive -> block sums -> add back (exclusive)
__global__ __launch_bounds__(1024) void scan1_kernel(const int* __restrict__ hist,
                                                     int* __restrict__ tmp,
                                                     int* __restrict__ bsums){
  __shared__ int buf[1024];
  int b = blockIdx.x, tid = threadIdx.x;
  int i = b*1024 + tid;
  int v = (i < N_NODES) ? hist[i] : 0;
  buf[tid] = v;
  __syncthreads();
  for (int off = 1; off < 1024; off <<= 1){
    int t = (tid >= off) ? buf[tid-off] : 0;
    __syncthreads();
    buf[tid] += t;
    __syncthreads();
  }
  if (i < N_NODES) tmp[i] = buf[tid];       // inclusive
  if (tid == 1023) bsums[b] = buf[1023];
}

__global__ void scan2_kernel(int* __restrict__ bsums, int* __restrict__ offsets){
  if (threadIdx.x == 0){
    int run = 0;
    for (int b = 0; b < SCAN_BLK; b++){ int v = bsums[b]; bsums[b] = run; run += v; }
    offsets[N_NODES] = run;
  }
}

__global__ __launch_bounds__(1024) void scan3_kernel(int* __restrict__ offsets,
                                                     int* __restrict__ hist,
                                                     const int* __restrict__ bsums){
  int b = blockIdx.x, tid = threadIdx.x;
  int i = b*1024 + tid;
  if (i >= N_NODES) return;
  int incl = offsets[i];
  int h = hist[i];
  int excl = incl - h + bsums[b];
  offsets[i] = excl;
  hist[i] = excl;       // cursor copy for perm_kernel
}

// perm + pre-gather: emits sortedSrc[q] and dtype-converted sortedEA[q]
__global__ void perm_kernel(const void* __restrict__ in1, const void* __restrict__ in2,
                            const int* __restrict__ flags, int* __restrict__ cursor,
                            int* __restrict__ sortedSrc, float2* __restrict__ sortedEA){
  int e = blockIdx.x*256 + threadIdx.x;
  if (e >= N_EDGES) return;
  const int f1 = flags[1], f = flags[0];
  const int* ei  = (const int*)(f1 ? in1 : in2);
  const void* eav = f1 ? in2 : in1;
  int d = clampi(ei[N_EDGES + e], 0, N_NODES-1);
  int s = clampi(ei[e], 0, N_NODES-1);
  float a0, a1;
  if (f){ const u16* e16 = (const u16*)eav; a0 = bu2f(e16[2*e]); a1 = bu2f(e16[2*e+1]); }
  else  { const float* e32 = (const float*)eav; a0 = e32[2*e]; a1 = e32[2*e+1]; }
  int pos = atomicAdd(&cursor[d], 1);
  pos = clampi(pos, 0, N_EDGES-1);
  sortedSrc[pos] = s;
  sortedEA[pos] = make_float2(a0, a1);
}

// ---------------- pooling ----------------

__global__ __launch_bounds__(128) void pool_kernel(
    const void* __restrict__ xv, const int* __restrict__ batch,
    float* __restrict__ xsum, int* __restrict__ counts, const int* __restrict__ flags)
{
  int c = threadIdx.x;
  int f = flags[0];
  int n0 = blockIdx.x * 32;
  int nend = min(n0 + 32, N_NODES);
  float acc = 0.f; int cnt = 0;
  int curb = clampi(batch[n0], 0, B_DIM-1);
  for (int n = n0; n < nend; n++){
    int b = clampi(batch[n], 0, B_DIM-1);
    if (b != curb){
      atomicAdd(&xsum[curb*C_DIM + c], acc);
      if (c == 0) atomicAdd(&counts[curb], cnt);
      acc = 0.f; cnt = 0; curb = b;
    }
    acc += ldf(xv, (size_t)n*C_DIM + c, f);
    cnt++;
  }
  atomicAdd(&xsum[curb*C_DIM + c], acc);
  if (c == 0) atomicAdd(&counts[curb], cnt);
}

// ---------------- GRU (+ mean finalize folded in) ----------------

__global__ __launch_bounds__(384) void gru_kernel(
    const float* __restrict__ xsum, const int* __restrict__ counts,
    const float* __restrict__ Wih, const float* __restrict__ bih,
    const float* __restrict__ Whh, const float* __restrict__ bhh,
    float* __restrict__ tokens)
{
  int b = blockIdx.x, j = threadIdx.x;  // j in [0,384)
  __shared__ float xm[C_DIM], h[C_DIM], gh[3*C_DIM], sgi[3*C_DIM];
  __shared__ float mxS;
  if (j == 0){
    int m = 1;
    for (int bb = 0; bb < B_DIM; bb++) m = max(m, counts[bb]);
    mxS = (float)m;
  }
  __syncthreads();
  if (j < C_DIM){ xm[j] = xsum[b*C_DIM + j] / mxS; h[j] = 0.f; }
  __syncthreads();
  float gi = bih[j];
  for (int k = 0; k < C_DIM; k++) gi = fmaf(xm[k], Wih[k*384 + j], gi);
  sgi[j] = gi;
  __syncthreads();
  for (int t = 0; t < L_DIM; t++){
    float acc = bhh[j];
    #pragma unroll 4
    for (int k = 0; k < C_DIM; k++) acc = fmaf(h[k], Whh[k*384 + j], acc);
    gh[j] = acc;
    __syncthreads();
    if (j < C_DIM){
      float r  = sigmoidf_(sgi[j] + gh[j]);
      float z  = sigmoidf_(sgi[C_DIM + j] + gh[C_DIM + j]);
      float nn = tanhf(sgi[2*C_DIM + j] + r*gh[2*C_DIM + j]);
      float hn = (1.f - z)*nn + z*h[j];
      h[j] = hn;
      tokens[((size_t)b*L_DIM + t)*C_DIM + j] = hn;
    }
    __syncthreads();
  }
}

// ---------------- token projection (Win) ----------------

__global__ __launch_bounds__(256) void token_proj_kernel(
    const float* __restrict__ tokens, const float* __restrict__ Win,
    float* __restrict__ x_in, float* __restrict__ z_last)
{
  int row = blockIdx.x;   // b*L + t
  int d = threadIdx.x;    // [0,256)
  __shared__ float tok[C_DIM];
  if (d < C_DIM) tok[d] = tokens[(size_t)row*C_DIM + d];
  __syncthreads();
  float acc = 0.f;
  for (int k = 0; k < C_DIM; k++) acc = fmaf(tok[k], Win[k*512 + d], acc);
  x_in[(size_t)row*D_DIM + d] = acc;
  if ((row & (L_DIM-1)) == L_DIM-1){
    float acc2 = 0.f;
    for (int k = 0; k < C_DIM; k++) acc2 = fmaf(tok[k], Win[k*512 + D_DIM + d], acc2);
    z_last[(row >> 5)*D_DIM + d] = acc2;
  }
}

// ---------------- xproj (conv+silu folded in) ----------------

__global__ __launch_bounds__(256) void xproj_kernel(
    const float* __restrict__ x_in, const float* __restrict__ cw,
    const float* __restrict__ cb, const float* __restrict__ Wx,
    const float* __restrict__ Wdt, const float* __restrict__ bdt,
    float* __restrict__ dt, float* __restrict__ Bp, float* __restrict__ Cp,
    float* __restrict__ x_c)
{
  int row = blockIdx.x; int tid = threadIdx.x;  // tid = d in [0,256)
  int t = row & (L_DIM-1);
  __shared__ float xr[D_DIM];
  __shared__ float dtr[R_DIM];
  float acc0 = cb[tid];
  #pragma unroll
  for (int k = 0; k < K_CONV; k++){
    int tt = t + k - (K_CONV-1);
    if (tt >= 0) acc0 = fmaf(cw[tid*K_CONV + k], x_in[(size_t)(row + tt - t)*D_DIM + tid], acc0);
  }
  float xcv = acc0 * sigmoidf_(acc0);
  x_c[(size_t)row*D_DIM + tid] = xcv;
  xr[tid] = xcv;
  __syncthreads();
  float acc = 0.f;
  #pragma unroll 4
  for (int k = 0; k < D_DIM; k++) acc = fmaf(xr[k], Wx[k*264 + tid], acc);
  if (tid < R_DIM)              dtr[tid] = acc;
  else if (tid < R_DIM+S_DIM)   Bp[(size_t)row*S_DIM + tid - R_DIM] = acc;
  else                          Cp[(size_t)row*S_DIM + tid - (R_DIM+S_DIM)] = acc;
  if (tid < 264 - D_DIM){
    float acc2 = 0.f;
    #pragma unroll 4
    for (int k = 0; k < D_DIM; k++) acc2 = fmaf(xr[k], Wx[k*264 + D_DIM + tid], acc2);
    Cp[(size_t)row*S_DIM + (D_DIM - (R_DIM+S_DIM)) + tid] = acc2;
  }
  __syncthreads();
  float a = bdt[tid];
  #pragma unroll
  for (int r = 0; r < R_DIM; r++) a = fmaf(dtr[r], Wdt[r*D_DIM + tid], a);
  dt[(size_t)row*D_DIM + tid] = (a > 20.f) ? a : log1pf(expf(a));
}

// ---------------- SSM scan ----------------

__global__ __launch_bounds__(256) void ssm_kernel(
    const float* __restrict__ dt, const float* __restrict__ Bp,
    const float* __restrict__ Cp, const float* __restrict__ x_c,
    const float* __restrict__ A_log, const float* __restrict__ Dp_,
    const float* __restrict__ z_last, float* __restrict__ y_last)
{
  int wid = (blockIdx.x*256 + threadIdx.x) >> 6;
  int lane = threadIdx.x & 63;
  int b = wid >> 8, d = wid & (D_DIM-1);
  int s0 = lane*2;
  float A0 = -expf(A_log[d*S_DIM + s0]);
  float A1 = -expf(A_log[d*S_DIM + s0 + 1]);
  float h0 = 0.f, h1 = 0.f;
  for (int t = 0; t < L_DIM; t++){
    int row = b*L_DIM + t;
    float dtv = dt[(size_t)row*D_DIM + d];
    float xv  = x_c[(size_t)row*D_DIM + d];
    float bx = dtv * xv;
    float2 Bv = ((const float2*)(Bp + (size_t)row*S_DIM))[lane];
    h0 = fmaf(expf(dtv*A0), h0, bx*Bv.x);
    h1 = fmaf(expf(dtv*A1), h1, bx*Bv.y);
  }
  int row = b*L_DIM + (L_DIM-1);
  float2 Cv = ((const float2*)(Cp + (size_t)row*S_DIM))[lane];
  float y = h0*Cv.x + h1*Cv.y;
  #pragma unroll
  for (int off = 32; off; off >>= 1) y += __shfl_down(y, off);
  if (lane == 0){
    float xc = x_c[(size_t)row*D_DIM + d];
    float yv = y + Dp_[d]*xc;
    float z  = z_last[b*D_DIM + d];
    yv *= z * sigmoidf_(z);
    y_last[b*D_DIM + d] = yv;
  }
}

// ---------------- proj = ln(y_last @ Wout) @ Wm1[8C:] ----------------

__device__ __forceinline__ float block_sum_128(float v, float* red){
  int c = threadIdx.x;
  red[c] = v; __syncthreads();
  if (c < 64) red[c] += red[c+64];
  __syncthreads();
  if (c < 64){
    float r = red[c];
    #pragma unroll
    for (int off = 32; off; off >>= 1) r += __shfl_down(r, off);
    if (c == 0) red[0] = r;
  }
  __syncthreads();
  float out = red[0];
  __syncthreads();
  return out;
}

__global__ __launch_bounds__(128) void xm_kernel(
    const float* __restrict__ y_last, const float* __restrict__ Wout,
    const float* __restrict__ g_m, const float* __restrict__ b_m,
    const float* __restrict__ Wm1x, float* __restrict__ proj)
{
  int b = blockIdx.x, c = threadIdx.x;
  __shared__ float yr[D_DIM];
  __shared__ float red[C_DIM];
  __shared__ float xmr[C_DIM];
  yr[c]        = y_last[b*D_DIM + c];
  yr[C_DIM+c]  = y_last[b*D_DIM + C_DIM + c];
  __syncthreads();
  float acc = 0.f;
  for (int k = 0; k < D_DIM; k++) acc = fmaf(yr[k], Wout[k*C_DIM + c], acc);
  float mean = block_sum_128(acc, red) * (1.f/C_DIM);
  float dv = acc - mean;
  float var = block_sum_128(dv*dv, red) * (1.f/C_DIM);
  float mo = dv*rsqrtf(var + 1e-5f)*g_m[c] + b_m[c];
  xmr[c] = mo;
  __syncthreads();
  float p = 0.f;
  for (int k = 0; k < C_DIM; k++) p = fmaf(xmr[k], Wm1x[k*C_DIM + c], p);
  proj[b*C_DIM + c] = p;
}

// ---------------- fused graph path (r9 structure) + mlp1 + mlp2 + final LN ----------------
// 128 threads, GROUP=4. c = threadIdx.x. Gather uses pre-sorted src/EA (2-deep chain).

__global__ __launch_bounds__(128) void graph_kernel(
    const void* __restrict__ xv,
    const int* __restrict__ sortedSrc, const float2* __restrict__ sortedEA,
    const int* __restrict__ offsets,
    const float* __restrict__ WeF, const float* __restrict__ beF,
    const float* __restrict__ WcF, const float* __restrict__ bcF,
    const float* __restrict__ Wm1F, const float* __restrict__ bm1F,
    const float* __restrict__ proj, const int* __restrict__ batch,
    const float* __restrict__ ghF, const float* __restrict__ bhF,
    const float* __restrict__ Wm2F, const float* __restrict__ bm2F,
    const float* __restrict__ goF, const float* __restrict__ boF,
    const int* __restrict__ flags, void* __restrict__ out)
{
  const int c = threadIdx.x;
  const int f = flags[0];
  const u16*  x16 = (const u16*)xv;  const float* x32 = (const float*)xv;

  __shared__ float aggS[GROUP][8][C_DIM];   // 16 KB
  __shared__ float xsS[GROUP][C_DIM];       // 2 KB (aliased as h1S in phases 3/4)
  __shared__ float red[C_DIM];              // 0.5 KB
  float (*h1S)[C_DIM] = xsS;                // xsS dead after phase 2; barriers separate

  float we0[8], we1[8], beh[8];
  #pragma unroll
  for (int h = 0; h < 8; h++){
    we0[h] = WeF[h*2*C_DIM + c];
    we1[h] = WeF[h*2*C_DIM + C_DIM + c];
    beh[h] = beF[h*C_DIM + c];
  }
  const int nbase = blockIdx.x * GROUP;

  // ---- phase 1: edge gather (2-edge-unrolled, dual x-prefetch; chain = src->x only) ----
  #pragma unroll
  for (int g = 0; g < GROUP; g++){
    int n = nbase + g;
    float a[8] = {0,0,0,0,0,0,0,0};
    int q0 = clampi(offsets[n],   0, N_EDGES);
    int q1 = clampi(offsets[n+1], q0, N_EDGES);
    int cnt = q1 - q0;
    float xa = 0.f, xb = 0.f;
    float2 ea0 = make_float2(0.f, 0.f), ea1 = make_float2(0.f, 0.f);
    if (cnt > 0){
      int s = clampi(sortedSrc[q0], 0, N_NODES-1);
      ea0 = sortedEA[q0];
      xa = f ? bu2f(x16[(size_t)s*C_DIM + c]) : x32[(size_t)s*C_DIM + c];
    }
    if (cnt > 1){
      int s = clampi(sortedSrc[q0+1], 0, N_NODES-1);
      ea1 = sortedEA[q0+1];
      xb = f ? bu2f(x16[(size_t)s*C_DIM + c]) : x32[(size_t)s*C_DIM + c];
    }
    for (int j = 0; j < cnt; j += 2){
      float x0 = xa, x1 = xb;
      float2 e0c = ea0, e1c = ea1;
      int jp = j + 2, jq = j + 3;
      if (jp < cnt){
        int s = clampi(sortedSrc[q0+jp], 0, N_NODES-1);
        ea0 = sortedEA[q0+jp];
        xa = f ? bu2f(x16[(size_t)s*C_DIM + c]) : x32[(size_t)s*C_DIM + c];
      }
      if (jq < cnt){
        int s = clampi(sortedSrc[q0+jq], 0, N_NODES-1);
        ea1 = sortedEA[q0+jq];
        xb = f ? bu2f(x16[(size_t)s*C_DIM + c]) : x32[(size_t)s*C_DIM + c];
      }
      #pragma unroll
      for (int h = 0; h < 8; h++)
        a[h] += fmaxf(fmaf(e0c.x, we0[h], fmaf(e0c.y, we1[h], x0 + beh[h])), 0.f);
      if (j + 1 < cnt){
        #pragma unroll
        for (int h = 0; h < 8; h++)
          a[h] += fmaxf(fmaf(e1c.x, we0[h], fmaf(e1c.y, we1[h], x1 + beh[h])), 0.f);
      }
    }
    #pragma unroll
    for (int h = 0; h < 8; h++) aggS[g][h][c] = a[h];
  }
  __syncthreads();

  // ---- phase 2: per-head matmuls (scalar coalesced w-loads) ----
  float p[GROUP] = {0,0,0,0};
  for (int h = 0; h < 8; h++){
    float accg[GROUP];
    #pragma unroll
    for (int g = 0; g < GROUP; g++) accg[g] = bcF[h*C_DIM + c];
    const float* wc = WcF + (size_t)h*C_DIM*C_DIM;
    for (int k = 0; k < C_DIM; k++){
      float w = wc[k*C_DIM + c];
      #pragma unroll
      for (int g = 0; g < GROUP; g++) accg[g] = fmaf(aggS[g][h][k], w, accg[g]);
    }
    __syncthreads();
    #pragma unroll
    for (int g = 0; g < GROUP; g++) xsS[g][c] = fmaxf(accg[g], 0.f);
    __syncthreads();
    const float* wm = Wm1F + (size_t)h*C_DIM*C_DIM;
    for (int k = 0; k < C_DIM; k++){
      float w = wm[k*C_DIM + c];
      #pragma unroll
      for (int g = 0; g < GROUP; g++) p[g] = fmaf(xsS[g][k], w, p[g]);
    }
  }

  // ---- phase 3: mlp1 LN + relu -> h1S (aliased onto xsS; safe via barriers) ----
  #pragma unroll
  for (int g = 0; g < GROUP; g++){
    int n = nbase + g;
    int bi = clampi(batch[n], 0, B_DIM-1);
    float val = p[g] + bm1F[c] + proj[bi*C_DIM + c];
    __syncthreads();
    float mean = block_sum_128(val, red) * (1.f/C_DIM);
    float dv = val - mean;
    float var = block_sum_128(dv*dv, red) * (1.f/C_DIM);
    float v = dv*rsqrtf(var + 1e-5f)*ghF[c] + bhF[c];
    h1S[g][c] = fmaxf(v, 0.f);
  }
  __syncthreads();

  // ---- phase 4: mlp2 + residual + final LN -> out ----
  float acc2[GROUP];
  #pragma unroll
  for (int g = 0; g < GROUP; g++) acc2[g] = bm2F[c];
  for (int k = 0; k < C_DIM; k++){
    float w = Wm2F[k*C_DIM + c];
    #pragma unroll
    for (int g = 0; g < GROUP; g++) acc2[g] = fmaf(h1S[g][k], w, acc2[g]);
  }
  #pragma unroll
  for (int g = 0; g < GROUP; g++){
    int n = nbase + g;
    float acc = acc2[g] + ldf(xv, (size_t)n*C_DIM + c, f);
    float mean = block_sum_128(acc, red) * (1.f/C_DIM);
    float dv = acc - mean;
    float var = block_sum_128(dv*dv, red) * (1.f/C_DIM);
    float v = dv*rsqrtf(var + 1e-5f)*goF[c] + boF[c];
    stf(out, (size_t)n*C_DIM + c, f, v);
  }
}

// ---------------- launcher ----------------

extern "C" void kernel_launch(void* const* d_in, const int* in_sizes, int n_in,
                              void* d_out, int out_size, void* d_ws, size_t ws_size,
                              hipStream_t stream)
{
  const void* x      = d_in[0];
  const void* in1    = d_in[1];
  const void* in2    = d_in[2];
  const int*  batch  = (const int*)d_in[3];
  (void)in_sizes; (void)n_in; (void)out_size; (void)ws_size;

  char* ws = (char*)d_ws;
  size_t off = 0;
  auto alloc = [&](size_t nbytes)->char*{
    char* p = ws + off;
    off += (nbytes + 255) & ~(size_t)255;
    return p;
  };
  int*   flags = (int*)alloc(8);
  float* arena = (float*)alloc((size_t)ARENA_TOTAL*4);
  int* hist    = (int*)alloc((size_t)N_NODES*4);          // becomes cursor after scan
  int* offsets = (int*)alloc((size_t)(N_NODES+1)*4);
  int* bsums   = (int*)alloc((size_t)SCAN_BLK*4);
  int* sortedSrc = (int*)alloc((size_t)N_EDGES*4);
  float2* sortedEA = (float2*)alloc((size_t)N_EDGES*8);
  float* proj   = (float*)alloc((size_t)B_DIM*C_DIM*4);
  float* xsum   = (float*)alloc((size_t)B_DIM*C_DIM*4);
  int*   counts = (int*)alloc((size_t)B_DIM*4);
  float* tokens = (float*)alloc((size_t)B_DIM*L_DIM*C_DIM*4);  // reused as Bp
  float* x_in   = (float*)alloc((size_t)B_DIM*L_DIM*D_DIM*4);  // reused as dtb
  float* x_c    = (float*)alloc((size_t)B_DIM*L_DIM*D_DIM*4);
  float* Cp     = (float*)alloc((size_t)B_DIM*L_DIM*S_DIM*4);
  float* z_last = (float*)alloc((size_t)B_DIM*D_DIM*4);
  float* y_last = (float*)alloc((size_t)B_DIM*D_DIM*4);
  float* Bp  = tokens;
  float* dtb = x_in;

  // weight arena views (match kCum)
  float* WeF   = arena + 0;      float* beF   = arena + 2048;
  float* WcF   = arena + 3072;   float* bcF   = arena + 134144;
  float* WihF  = arena + 135168; float* WhhF  = arena + 184320;
  float* bihF  = arena + 233472; float* bhhF  = arena + 233856;
  float* WinF  = arena + 234240; float* cwF   = arena + 299776;
  float* cbF   = arena + 300800; float* WxF   = arena + 301056;
  float* WdtF  = arena + 368640; float* bdtF  = arena + 370688;
  float* AlF   = arena + 370944; float* DpF   = arena + 403712;
  float* WoutF = arena + 403968; float* gmF   = arena + 436736;
  float* bmF   = arena + 436864; float* Wm1F  = arena + 436992;
  float* bm1F  = arena + 584448; float* ghF   = arena + 584576;
  float* bhF   = arena + 584704; float* Wm2F  = arena + 584832;
  float* bm2F  = arena + 601216; float* goF   = arena + 601344;
  float* boF   = arena + 601472;

  // 0) detect dtype + edge-input order
  detect_kernel<<<1, 64, 0, stream>>>((const unsigned*)d_in[19],
                                      (const unsigned*)in1, (const unsigned*)in2, flags);

  // 1) all weight converts in one launch
  Ptrs ptrs;
  for (int i = 0; i < K_SEG; i++) ptrs.p[i] = d_in[4 + i];
  cvt_all_kernel<<<(ARENA_TOTAL + 255)/256, 256, 0, stream>>>(ptrs, arena, flags);

  // 2) counting sort of edges by dst (3-phase parallel scan + pre-gather)
  hipMemsetAsync(hist, 0, (size_t)N_NODES*4, stream);
  hist_kernel<<<(N_EDGES + 255)/256, 256, 0, stream>>>((const int*)in1, (const int*)in2, flags, hist);
  scan1_kernel<<<SCAN_BLK, 1024, 0, stream>>>(hist, offsets, bsums);
  scan2_kernel<<<1, 64, 0, stream>>>(bsums, offsets);
  scan3_kernel<<<SCAN_BLK, 1024, 0, stream>>>(offsets, hist, bsums);
  perm_kernel<<<(N_EDGES + 255)/256, 256, 0, stream>>>(in1, in2, flags, hist, sortedSrc, sortedEA);

  // 3) sequential path
  hipMemsetAsync(xsum, 0, (size_t)B_DIM*C_DIM*4 + 256, stream);  // xsum + counts
  pool_kernel<<<(N_NODES + 31)/32, 128, 0, stream>>>(x, batch, xsum, counts, flags);
  gru_kernel<<<B_DIM, 384, 0, stream>>>(xsum, counts, WihF, bihF, WhhF, bhhF, tokens);
  token_proj_kernel<<<B_DIM*L_DIM, 256, 0, stream>>>(tokens, WinF, x_in, z_last);
  xproj_kernel<<<B_DIM*L_DIM, 256, 0, stream>>>(x_in, cwF, cbF, WxF, WdtF, bdtF, dtb, Bp, Cp, x_c);
  ssm_kernel<<<(B_DIM*D_DIM)/4, 256, 0, stream>>>(dtb, Bp, Cp, x_c, AlF, DpF, z_last, y_last);
  xm_kernel<<<B_DIM, 128, 0, stream>>>(y_last, WoutF, gmF, bmF, Wm1F + 8*C_DIM*C_DIM, proj);

  // 4) fused graph path + mlp1 + mlp2 + final LN -> d_out
  graph_kernel<<<N_NODES/GROUP, 128, 0, stream>>>(
      x, sortedSrc, sortedEA, offsets, WeF, beF, WcF, bcF, Wm1F, bm1F,
      proj, batch, ghF, bhF, Wm2F, bm2F, goF, boF, flags, d_out);
}